// Round 14
// baseline (275.628 us; speedup 1.0000x reference)
//
#include <hip/hip_runtime.h>

typedef unsigned short u16;
typedef unsigned int u32;
typedef __attribute__((ext_vector_type(4))) float f32x4;
typedef __attribute__((ext_vector_type(8))) short bf16x8;
typedef __attribute__((ext_vector_type(8))) u16 u16x8;

// ---- helpers ----
__device__ __forceinline__ u16 f2b(float f) {
  union { float f; u32 u; } v; v.f = f;
  u32 r = v.u + 0x7FFFu + ((v.u >> 16) & 1u);
  return (u16)(r >> 16);
}
__device__ __forceinline__ float b2f(u16 h) {
  union { u32 u; float f; } v; v.u = ((u32)h) << 16;
  return v.f;
}
__device__ __forceinline__ void gload_lds16(const void* g, void* lds) {
  __builtin_amdgcn_global_load_lds(
      (__attribute__((address_space(1))) void*)(void*)g,
      (__attribute__((address_space(3))) void*)lds, 16, 0, 0);
}

// ---- cast x (fp32 -> bf16), vectorized 8/thread ----
__global__ __launch_bounds__(256) void cast_x_kernel(const float* __restrict__ x,
                                                     u16* __restrict__ xb, size_t n8) {
  size_t i = (size_t)blockIdx.x * blockDim.x + threadIdx.x;
  size_t stride = (size_t)gridDim.x * blockDim.x;
  for (; i < n8; i += stride) {
    const float4* p = (const float4*)(x + i * 8);
    float4 a = p[0], b = p[1];
    u16x8 o;
    o[0] = f2b(a.x); o[1] = f2b(a.y); o[2] = f2b(a.z); o[3] = f2b(a.w);
    o[4] = f2b(b.x); o[5] = f2b(b.y); o[6] = f2b(b.z); o[7] = f2b(b.w);
    *(u16x8*)(xb + i * 8) = o;
  }
}

// ---- transpose + cast: W[R][C] (fp32) -> WT[perm(C)][R] (bf16) ----
// PERM (Wqkv): c<768 -> c ; k: 768+h*64+w -> 768+h*128+w ;
//              v: 1536+h*64+w -> 768+h*128+64+w   (h = quotient, NOT bitmask)
template <bool PERM>
__global__ __launch_bounds__(256) void transpose_cast_kernel(const float* __restrict__ W,
                                                             u16* __restrict__ WT,
                                                             int R, int C) {
  __shared__ u16 tile[32][33];
  int rt = R >> 5;
  int tr = blockIdx.x % rt, tc = blockIdx.x / rt;
  int r0 = tr * 32, c0 = tc * 32;
#pragma unroll
  for (int i = 0; i < 4; ++i) {
    int r = (threadIdx.x >> 5) + i * 8, c = threadIdx.x & 31;
    tile[r][c] = f2b(W[(size_t)(r0 + r) * C + c0 + c]);
  }
  __syncthreads();
#pragma unroll
  for (int i = 0; i < 4; ++i) {
    int c = (threadIdx.x >> 5) + i * 8, r = threadIdx.x & 31;
    int cc = c0 + c;
    if (PERM && cc >= 768) {
      int t = cc - 768;
      int isv = (t >= 768) ? 1 : 0;
      int tk = t - isv * 768;
      cc = 768 + (tk >> 6) * 128 + isv * 64 + (tk & 63);
    }
    WT[(size_t)cc * R + r0 + r] = tile[r][c];
  }
}

// ============== 128x128 GEMM + fused ctx epilogue, compiler-scheduled ========
// C = A * BT^T ; bf16 in, fp32 acc ; K=768 (NT=24, BK=32). 256 thr, 4 waves
// (2Mx2N), per-wave 64x64 = 4x4 16x16 frags. 40KB LDS, 4 blocks/CU.
// KEY: no lgkmcnt pin between ds_reads and MFMAs -- compiler interleaves
// fine-grained lgkm waits so MFMA starts as soon as first operands land.
// Correctness: trailing lgkmcnt(0)+"memory" before barrier (reads complete
// pre-barrier); empty "memory" asm after barrier (no read hoisting).
template <bool G1, bool BIAS, bool BATCHB>
__global__ __launch_bounds__(256, 4) void gemm128_kernel(
    const u16* __restrict__ A, const u16* __restrict__ BT, void* __restrict__ Cv,
    void* __restrict__ Pw, const float* __restrict__ bias, int N, int lda, int ntile) {
  constexpr int K = 768;
  constexpr int NT = 24;
  __shared__ __align__(16) u16 lds[20480];     // As: 2x4096 | Bs: 3x4096 (40 KB)
  u16* Asb = lds;
  u16* Bsb = lds + 8192;
  const int tid = threadIdx.x;
  const int wave = tid >> 6, lane = tid & 63;
  const int lr = lane & 15, hi = lane >> 4;
  const int wr = wave >> 1, wc = wave & 1;

  // bijective XCD swizzle (grid % 8 == 0)
  const int cpx = gridDim.x >> 3;
  const int wg = (blockIdx.x & 7) * cpx + (blockIdx.x >> 3);
  const int tm = wg / ntile, tn = wg % ntile;

  const size_t rowA0 = (size_t)tm * 128;
  const size_t rowB0 = (size_t)tn * 128;
  const u16* BTb = BATCHB ? (BT + (size_t)(tm >> 5) * 589824) : BT;

  // ---- staging: linear LDS dest, inverse-swizzled source
  const int dby = tid * 16;
  const int sby = dby ^ (((dby >> 7) & 3) << 4);
  const int srow = sby >> 6;
  const int scol = (sby & 63) >> 1;
  const u16* pA = A + (rowA0 + srow) * (size_t)lda + scol;
  const u16* pB = BTb + (rowB0 + srow) * (size_t)K + scol;
  u16* Adst = Asb + wave * 512;
  u16* Bdst = Bsb + wave * 512;

  // ---- read-side swizzled bases
  const int flip = ((lr >> 1) & 3) << 4;
  const int baseA = ((((wr * 64 + lr) * 64) + hi * 16) ^ flip) >> 1;
  const int baseB = ((((wc * 64 + lr) * 64) + hi * 16) ^ flip) >> 1;

  f32x4 acc[4][4] = {};

#define STG_A(tt)                                                          \
  { const u16* _s = pA + (size_t)(tt) * 32;                                \
    u16* _d = Adst + ((tt) & 1) * 4096;                                    \
    gload_lds16(_s, _d); gload_lds16(_s + (size_t)64 * lda, _d + 2048); }
#define STG_B(tt)                                                          \
  { const u16* _s = pB + (size_t)(tt) * 32;                                \
    u16* _d = Bdst + ((tt) % 3) * 4096;                                    \
    gload_lds16(_s, _d); gload_lds16(_s + (size_t)64 * K, _d + 2048); }

  // prologue: A(0), B(0), B(1); wait A0+B0 (leave B1 in flight)
  STG_A(0); STG_B(0); STG_B(1);
  asm volatile("s_waitcnt vmcnt(2)" ::: "memory");
  __builtin_amdgcn_s_barrier();
  asm volatile("" ::: "memory");               // no read hoisting above barrier

#pragma unroll
  for (int t = 0; t < NT; ++t) {
    const u16* Ab = Asb + (t & 1) * 4096;
    const u16* Bb = Bsb + (t % 3) * 4096;
    bf16x8 a0 = *(const bf16x8*)&Ab[baseA];
    bf16x8 a1 = *(const bf16x8*)&Ab[baseA + 512];
    bf16x8 a2 = *(const bf16x8*)&Ab[baseA + 1024];
    bf16x8 a3 = *(const bf16x8*)&Ab[baseA + 1536];
    bf16x8 b0 = *(const bf16x8*)&Bb[baseB];
    bf16x8 b1 = *(const bf16x8*)&Bb[baseB + 512];
    bf16x8 b2 = *(const bf16x8*)&Bb[baseB + 1024];
    bf16x8 b3 = *(const bf16x8*)&Bb[baseB + 1536];
    if (t + 1 < NT) STG_A(t + 1);
    if (t + 2 < NT) STG_B(t + 2);
    // NO lgkm pin here: compiler interleaves waits with the MFMA stream.
    __builtin_amdgcn_s_setprio(1);
    acc[0][0] = __builtin_amdgcn_mfma_f32_16x16x32_bf16(a0, b0, acc[0][0], 0, 0, 0);
    acc[0][1] = __builtin_amdgcn_mfma_f32_16x16x32_bf16(a0, b1, acc[0][1], 0, 0, 0);
    acc[0][2] = __builtin_amdgcn_mfma_f32_16x16x32_bf16(a0, b2, acc[0][2], 0, 0, 0);
    acc[0][3] = __builtin_amdgcn_mfma_f32_16x16x32_bf16(a0, b3, acc[0][3], 0, 0, 0);
    acc[1][0] = __builtin_amdgcn_mfma_f32_16x16x32_bf16(a1, b0, acc[1][0], 0, 0, 0);
    acc[1][1] = __builtin_amdgcn_mfma_f32_16x16x32_bf16(a1, b1, acc[1][1], 0, 0, 0);
    acc[1][2] = __builtin_amdgcn_mfma_f32_16x16x32_bf16(a1, b2, acc[1][2], 0, 0, 0);
    acc[1][3] = __builtin_amdgcn_mfma_f32_16x16x32_bf16(a1, b3, acc[1][3], 0, 0, 0);
    acc[2][0] = __builtin_amdgcn_mfma_f32_16x16x32_bf16(a2, b0, acc[2][0], 0, 0, 0);
    acc[2][1] = __builtin_amdgcn_mfma_f32_16x16x32_bf16(a2, b1, acc[2][1], 0, 0, 0);
    acc[2][2] = __builtin_amdgcn_mfma_f32_16x16x32_bf16(a2, b2, acc[2][2], 0, 0, 0);
    acc[2][3] = __builtin_amdgcn_mfma_f32_16x16x32_bf16(a2, b3, acc[2][3], 0, 0, 0);
    acc[3][0] = __builtin_amdgcn_mfma_f32_16x16x32_bf16(a3, b0, acc[3][0], 0, 0, 0);
    acc[3][1] = __builtin_amdgcn_mfma_f32_16x16x32_bf16(a3, b1, acc[3][1], 0, 0, 0);
    acc[3][2] = __builtin_amdgcn_mfma_f32_16x16x32_bf16(a3, b2, acc[3][2], 0, 0, 0);
    acc[3][3] = __builtin_amdgcn_mfma_f32_16x16x32_bf16(a3, b3, acc[3][3], 0, 0, 0);
    __builtin_amdgcn_s_setprio(0);
    if (t < NT - 2) {
      asm volatile("s_waitcnt vmcnt(2)" ::: "memory");
    } else if (t == NT - 2) {
      asm volatile("s_waitcnt vmcnt(0)" ::: "memory");
    }
    // all this tile's ds_reads must complete before the rendezvous
    asm volatile("s_waitcnt lgkmcnt(0)" ::: "memory");
    if (t + 1 < NT) __builtin_amdgcn_s_barrier();
    asm volatile("" ::: "memory");             // next tile's reads stay below
  }
#undef STG_A
#undef STG_B

  const int ocol0 = tn * 128 + wc * 64;
  const int orow0 = tm * 128 + wr * 64;

  if (!G1) {
    // ---- plain fp32+bias path, non-temporal stores (out never re-read)
#pragma unroll
    for (int mf = 0; mf < 4; ++mf)
#pragma unroll
      for (int nf = 0; nf < 4; ++nf) {
        const int col = ocol0 + nf * 16 + lr;
        const float bv = BIAS ? bias[col] : 0.0f;
#pragma unroll
        for (int q = 0; q < 4; ++q) {
          const int row = orow0 + mf * 16 + hi * 4 + q;
          __builtin_nontemporal_store(acc[mf][nf][q] + bv,
                                      &((float*)Cv)[(size_t)row * N + col]);
        }
      }
  } else if (tn < 6) {
    // ---- q path: softmax, LDS-bounce, full-line 16B/lane nt stores
    __syncthreads();                         // all main-loop LDS reads done
    u16* wlds = lds + wave * 4352;           // per-wave [64][68]
#pragma unroll
    for (int mf = 0; mf < 4; ++mf) {
#pragma unroll
      for (int q = 0; q < 4; ++q) {
        float v0 = acc[mf][0][q], v1 = acc[mf][1][q];
        float v2 = acc[mf][2][q], v3 = acc[mf][3][q];
        float mx = fmaxf(fmaxf(v0, v1), fmaxf(v2, v3));
#pragma unroll
        for (int s = 1; s <= 8; s <<= 1) mx = fmaxf(mx, __shfl_xor(mx, s, 64));
        float e0 = __expf(v0 - mx), e1 = __expf(v1 - mx);
        float e2 = __expf(v2 - mx), e3 = __expf(v3 - mx);
        float sm = e0 + e1 + e2 + e3;
#pragma unroll
        for (int s = 1; s <= 8; s <<= 1) sm += __shfl_xor(sm, s, 64);
        float inv = 1.0f / sm;
        const int rw = mf * 16 + hi * 4 + q;
        wlds[rw * 68 + 0 * 16 + lr] = f2b(e0 * inv);
        wlds[rw * 68 + 1 * 16 + lr] = f2b(e1 * inv);
        wlds[rw * 68 + 2 * 16 + lr] = f2b(e2 * inv);
        wlds[rw * 68 + 3 * 16 + lr] = f2b(e3 * inv);
      }
    }
    // per-wave drain (own region, own data; lgkmcnt orders write->read)
#pragma unroll
    for (int it = 0; it < 8; ++it) {
      const int row = it * 8 + (lane >> 3);
      const int c8 = (lane & 7) * 8;
      u16x8 v = *(const u16x8*)&wlds[row * 68 + c8];
      __builtin_nontemporal_store(
          v, (u16x8*)((u16*)Cv + (size_t)(orow0 + row) * 768 + ocol0 + c8));
    }
  } else {
    // ---- kv head tile: softmax k (wc==0), transpose to LDS, ctx = k^T v
    const int h = tn - 6;
    if (wc == 0) {
#pragma unroll
      for (int mf = 0; mf < 4; ++mf)
#pragma unroll
        for (int q = 0; q < 4; ++q) {
          float v0 = acc[mf][0][q], v1 = acc[mf][1][q];
          float v2 = acc[mf][2][q], v3 = acc[mf][3][q];
          float mx = fmaxf(fmaxf(v0, v1), fmaxf(v2, v3));
#pragma unroll
          for (int s = 1; s <= 8; s <<= 1) mx = fmaxf(mx, __shfl_xor(mx, s, 64));
          float e0 = __expf(v0 - mx), e1 = __expf(v1 - mx);
          float e2 = __expf(v2 - mx), e3 = __expf(v3 - mx);
          float sm = e0 + e1 + e2 + e3;
#pragma unroll
          for (int s = 1; s <= 8; s <<= 1) sm += __shfl_xor(sm, s, 64);
          float inv = 1.0f / sm;
          acc[mf][0][q] = e0 * inv; acc[mf][1][q] = e1 * inv;
          acc[mf][2][q] = e2 * inv; acc[mf][3][q] = e3 * inv;
        }
    }
    __syncthreads();                         // all main-loop LDS reads done
    u16* kT = lds;                           // [64][136]
    u16* vT = lds + 8704;                    // [64][136]
    u16* tgt = wc ? vT : kT;
#pragma unroll
    for (int mf = 0; mf < 4; ++mf)
#pragma unroll
      for (int nf = 0; nf < 4; ++nf)
#pragma unroll
        for (int q = 0; q < 4; ++q)
          tgt[(nf * 16 + lr) * 136 + wr * 64 + mf * 16 + hi * 4 + q] =
              f2b(acc[mf][nf][q]);
    __syncthreads();
    // acc is dead now -> reuse acc[0][0..3] as ctx accumulators (no spill)
    {
      f32x4 z = {0.0f, 0.0f, 0.0f, 0.0f};
      acc[0][0] = z; acc[0][1] = z; acc[0][2] = z; acc[0][3] = z;
    }
#pragma unroll
    for (int ks = 0; ks < 4; ++ks) {
      bf16x8 ak = *(const bf16x8*)&kT[(wave * 16 + lr) * 136 + ks * 32 + hi * 8];
#pragma unroll
      for (int ef = 0; ef < 4; ++ef) {
        bf16x8 bv = *(const bf16x8*)&vT[(ef * 16 + lr) * 136 + ks * 32 + hi * 8];
        acc[0][ef] = __builtin_amdgcn_mfma_f32_16x16x32_bf16(ak, bv, acc[0][ef], 0, 0, 0);
      }
    }
    __syncthreads();                         // kT/vT reads done; reuse as bounce
    u16* blds = lds;                         // [64][68]
#pragma unroll
    for (int ef = 0; ef < 4; ++ef)
#pragma unroll
      for (int q = 0; q < 4; ++q)
        blds[(wave * 16 + hi * 4 + q) * 68 + ef * 16 + lr] = f2b(acc[0][ef][q]);
    __syncthreads();
    u16* pdst = (u16*)Pw + ((size_t)tm * 12 + h) * 4096;
#pragma unroll
    for (int it = 0; it < 2; ++it) {
      const int seg = it * 256 + tid;
      const int row = seg >> 3, c8 = (seg & 7) * 8;
      u16x8 v = *(const u16x8*)&blds[row * 68 + c8];
      __builtin_nontemporal_store(v, (u16x8*)(pdst + row * 64 + c8));
    }
  }
}

// ---- reduce bf16 partials (32 m-tiles) -> ctxD[bh][d*64+e] bf16 ----
__global__ __launch_bounds__(256) void ctx_reduce_kernel(const u16* __restrict__ partial,
                                                         u16* __restrict__ ctxD) {
  int idx = (blockIdx.x * 256 + threadIdx.x) * 8;   // over 96*4096
  int bh = idx >> 12;
  int b = bh / 12, h = bh % 12;
  int de = idx & 4095;
  const u16* base = partial + ((size_t)(b * 32) * 12 + h) * 4096 + de;
  float s[8] = {};
#pragma unroll 4
  for (int i = 0; i < 32; ++i) {
    u16x8 v = *(const u16x8*)(base + (size_t)i * 49152);
#pragma unroll
    for (int j = 0; j < 8; ++j) s[j] += b2f(v[j]);
  }
  u16x8 o;
#pragma unroll
  for (int j = 0; j < 8; ++j) o[j] = f2b(s[j]);
  *(u16x8*)(ctxD + (size_t)bh * 4096 + de) = o;
}

// ---- W2T[b][c'][h*64+d] = sum_e WprojT[c'][h*64+e] * ctxD[bh][d*64+e] ----
__global__ __launch_bounds__(256) void make_w2_kernel(const u16* __restrict__ WprojT,
                                                      const u16* __restrict__ ctxD,
                                                      u16* __restrict__ BT2) {
  __shared__ u16 qs[128 * 64];
  __shared__ u16 cs[64 * 64];
  int bid = blockIdx.x;
  int b = bid / 72, rest = bid % 72;
  int h = rest / 6, ct = rest % 6;
  int bh = b * 12 + h;
  int tid = threadIdx.x, wave = tid >> 6, lane = tid & 63;
  int lr = lane & 15, lk = (lane >> 4) << 3;
#pragma unroll
  for (int it = 0; it < 4; ++it) {
    int u = it * 256 + tid;
    int r = u >> 3, c8 = (u & 7) * 8;
    gload_lds16(WprojT + (size_t)(ct * 128 + r) * 768 + h * 64 + c8,
                &qs[(it * 256 + wave * 64) * 8]);
  }
#pragma unroll
  for (int it = 0; it < 2; ++it) {
    int u = it * 256 + tid;
    gload_lds16(ctxD + (size_t)bh * 4096 + u * 8, &cs[(it * 256 + wave * 64) * 8]);
  }
  asm volatile("s_waitcnt vmcnt(0)" ::: "memory");
  __syncthreads();
  f32x4 acc[2][4] = {};
#pragma unroll
  for (int ks = 0; ks < 2; ++ks) {
    bf16x8 bv[4];
#pragma unroll
    for (int jt = 0; jt < 4; ++jt) bv[jt] = *(const bf16x8*)&cs[(jt * 16 + lr) * 64 + ks * 32 + lk];
#pragma unroll
    for (int i = 0; i < 2; ++i) {
      bf16x8 af = *(const bf16x8*)&qs[(wave * 32 + i * 16 + lr) * 64 + ks * 32 + lk];
#pragma unroll
      for (int jt = 0; jt < 4; ++jt)
        acc[i][jt] = __builtin_amdgcn_mfma_f32_16x16x32_bf16(af, bv[jt], acc[i][jt], 0, 0, 0);
    }
  }
#pragma unroll
  for (int i = 0; i < 2; ++i)
#pragma unroll
    for (int jt = 0; jt < 4; ++jt)
#pragma unroll
      for (int q = 0; q < 4; ++q) {
        int cp = ct * 128 + wave * 32 + i * 16 + (lane >> 4) * 4 + q;
        int col = h * 64 + jt * 16 + lr;
        BT2[(size_t)b * 589824 + (size_t)cp * 768 + col] = f2b(acc[i][jt][q]);
      }
}

extern "C" void kernel_launch(void* const* d_in, const int* in_sizes, int n_in,
                              void* d_out, int out_size, void* d_ws, size_t ws_size,
                              hipStream_t stream) {
  const float* x = (const float*)d_in[0];
  const float* Wqkv = (const float*)d_in[1];
  const float* Wproj = (const float*)d_in[2];
  const float* bproj = (const float*)d_in[3];
  float* out = (float*)d_out;
  char* ws = (char*)d_ws;

  u16* xb      = (u16*)(ws);                     // 32768*768*2      = 50331648
  u16* WqkvT   = (u16*)(ws + 50331648);          // 2304*768*2       = 3538944
  u16* WprojT  = (u16*)(ws + 53870592);          // 768*768*2        = 1179648
  u16* qbuf    = (u16*)(ws + 55050240);          // 32768*768*2      = 50331648
  u16* partial = (u16*)(ws + 105381888);         // 256*12*4096*2    = 25165824
  u16* ctxD    = (u16*)(ws + 130547712);         // 96*4096*2        = 786432
  u16* BT2     = (u16*)(ws + 131334144);         // 8*768*768*2      = 9437184

  cast_x_kernel<<<2048, 256, 0, stream>>>(x, xb, (size_t)(32768ll * 768 / 8));
  transpose_cast_kernel<true><<<(768 / 32) * (2304 / 32), 256, 0, stream>>>(Wqkv, WqkvT, 768, 2304);
  transpose_cast_kernel<false><<<(768 / 32) * (768 / 32), 256, 0, stream>>>(Wproj, WprojT, 768, 768);

  // GEMM1: q -> softmax -> qbuf ; kv head tiles -> softmax k -> bf16 ctx partials
  gemm128_kernel<true, false, false><<<(32768 / 128) * (2304 / 128), 256, 0, stream>>>(
      xb, WqkvT, (void*)qbuf, (void*)partial, nullptr, 2304, 768, 2304 / 128);

  ctx_reduce_kernel<<<(96 * 4096) / (256 * 8), 256, 0, stream>>>(partial, ctxD);
  make_w2_kernel<<<8 * 12 * 6, 256, 0, stream>>>(WprojT, ctxD, BT2);

  // GEMM3: out = qbuf @ W2T_b^T + bias  (contiguous A, per-batch B)
  gemm128_kernel<false, true, true><<<(32768 / 128) * (768 / 128), 256, 0, stream>>>(
      qbuf, BT2, (void*)out, nullptr, bproj, 768, 768, 768 / 128);
}

// Round 15
// 267.594 us; speedup vs baseline: 1.0300x; 1.0300x over previous
//
#include <hip/hip_runtime.h>

typedef unsigned short u16;
typedef unsigned int u32;
typedef __attribute__((ext_vector_type(4))) float f32x4;
typedef __attribute__((ext_vector_type(8))) short bf16x8;
typedef __attribute__((ext_vector_type(8))) u16 u16x8;

// ---- helpers ----
__device__ __forceinline__ u16 f2b(float f) {
  union { float f; u32 u; } v; v.f = f;
  u32 r = v.u + 0x7FFFu + ((v.u >> 16) & 1u);
  return (u16)(r >> 16);
}
__device__ __forceinline__ float b2f(u16 h) {
  union { u32 u; float f; } v; v.u = ((u32)h) << 16;
  return v.f;
}
__device__ __forceinline__ void gload_lds16(const void* g, void* lds) {
  __builtin_amdgcn_global_load_lds(
      (__attribute__((address_space(1))) void*)(void*)g,
      (__attribute__((address_space(3))) void*)lds, 16, 0, 0);
}

// ---- cast x (fp32 -> bf16), vectorized 8/thread ----
__global__ __launch_bounds__(256) void cast_x_kernel(const float* __restrict__ x,
                                                     u16* __restrict__ xb, size_t n8) {
  size_t i = (size_t)blockIdx.x * blockDim.x + threadIdx.x;
  size_t stride = (size_t)gridDim.x * blockDim.x;
  for (; i < n8; i += stride) {
    const float4* p = (const float4*)(x + i * 8);
    float4 a = p[0], b = p[1];
    u16x8 o;
    o[0] = f2b(a.x); o[1] = f2b(a.y); o[2] = f2b(a.z); o[3] = f2b(a.w);
    o[4] = f2b(b.x); o[5] = f2b(b.y); o[6] = f2b(b.z); o[7] = f2b(b.w);
    *(u16x8*)(xb + i * 8) = o;
  }
}

// ---- transpose + cast: W[R][C] (fp32) -> WT[perm(C)][R] (bf16) ----
// PERM (Wqkv): c<768 -> c ; k: 768+h*64+w -> 768+h*128+w ;
//              v: 1536+h*64+w -> 768+h*128+64+w   (h = quotient, NOT bitmask)
template <bool PERM>
__global__ __launch_bounds__(256) void transpose_cast_kernel(const float* __restrict__ W,
                                                             u16* __restrict__ WT,
                                                             int R, int C) {
  __shared__ u16 tile[32][33];
  int rt = R >> 5;
  int tr = blockIdx.x % rt, tc = blockIdx.x / rt;
  int r0 = tr * 32, c0 = tc * 32;
#pragma unroll
  for (int i = 0; i < 4; ++i) {
    int r = (threadIdx.x >> 5) + i * 8, c = threadIdx.x & 31;
    tile[r][c] = f2b(W[(size_t)(r0 + r) * C + c0 + c]);
  }
  __syncthreads();
#pragma unroll
  for (int i = 0; i < 4; ++i) {
    int c = (threadIdx.x >> 5) + i * 8, r = threadIdx.x & 31;
    int cc = c0 + c;
    if (PERM && cc >= 768) {
      int t = cc - 768;
      int isv = (t >= 768) ? 1 : 0;
      int tk = t - isv * 768;
      cc = 768 + (tk >> 6) * 128 + isv * 64 + (tk & 63);
    }
    WT[(size_t)cc * R + r0 + r] = tile[r][c];
  }
}

// ============== 128x128 GEMM (round-8 loop) + fused ctx epilogue ==============
// C = A * BT^T ; bf16 in, fp32 acc ; K=768 (NT=24, BK=32). 256 thr, 4 waves
// (2Mx2N), per-wave 64x64 = 4x4 16x16 frags. 40KB LDS, 4 blocks/CU.
// Epilogues bounce tiles through LDS so ALL global stores are full 128B lines.
// G1: tn<6 -> softmax q -> qbuf ; tn>=6 (head h=tn-6) -> softmax k, LDS
//     transpose, ctx = k^T v -> bf16 partial[tm][h][64][64]. !G1: fp32 + bias.
template <bool G1, bool BIAS, bool BATCHB>
__global__ __launch_bounds__(256, 4) void gemm128_kernel(
    const u16* __restrict__ A, const u16* __restrict__ BT, void* __restrict__ Cv,
    void* __restrict__ Pw, const float* __restrict__ bias, int N, int lda, int ntile) {
  constexpr int K = 768;
  constexpr int NT = 24;
  __shared__ __align__(16) u16 lds[20480];     // As: 2x4096 | Bs: 3x4096 (40 KB)
  u16* Asb = lds;
  u16* Bsb = lds + 8192;
  const int tid = threadIdx.x;
  const int wave = tid >> 6, lane = tid & 63;
  const int lr = lane & 15, hi = lane >> 4;
  const int wr = wave >> 1, wc = wave & 1;

  // bijective XCD swizzle (grid % 8 == 0)
  const int cpx = gridDim.x >> 3;
  const int wg = (blockIdx.x & 7) * cpx + (blockIdx.x >> 3);
  const int tm = wg / ntile, tn = wg % ntile;

  const size_t rowA0 = (size_t)tm * 128;
  const size_t rowB0 = (size_t)tn * 128;
  const u16* BTb = BATCHB ? (BT + (size_t)(tm >> 5) * 589824) : BT;

  // ---- staging: linear LDS dest, inverse-swizzled source
  const int dby = tid * 16;
  const int sby = dby ^ (((dby >> 7) & 3) << 4);
  const int srow = sby >> 6;
  const int scol = (sby & 63) >> 1;
  const u16* pA = A + (rowA0 + srow) * (size_t)lda + scol;
  const u16* pB = BTb + (rowB0 + srow) * (size_t)K + scol;
  u16* Adst = Asb + wave * 512;
  u16* Bdst = Bsb + wave * 512;

  // ---- read-side swizzled bases
  const int flip = ((lr >> 1) & 3) << 4;
  const int baseA = ((((wr * 64 + lr) * 64) + hi * 16) ^ flip) >> 1;
  const int baseB = ((((wc * 64 + lr) * 64) + hi * 16) ^ flip) >> 1;

  f32x4 acc[4][4] = {};

#define STG_A(tt)                                                          \
  { const u16* _s = pA + (size_t)(tt) * 32;                                \
    u16* _d = Adst + ((tt) & 1) * 4096;                                    \
    gload_lds16(_s, _d); gload_lds16(_s + (size_t)64 * lda, _d + 2048); }
#define STG_B(tt)                                                          \
  { const u16* _s = pB + (size_t)(tt) * 32;                                \
    u16* _d = Bdst + ((tt) % 3) * 4096;                                    \
    gload_lds16(_s, _d); gload_lds16(_s + (size_t)64 * K, _d + 2048); }

  // prologue: A(0), B(0), B(1); wait A0+B0 (leave B1 in flight)
  STG_A(0); STG_B(0); STG_B(1);
  asm volatile("s_waitcnt vmcnt(2)" ::: "memory");
  __builtin_amdgcn_sched_barrier(0);
  __builtin_amdgcn_s_barrier();

#pragma unroll
  for (int t = 0; t < NT; ++t) {
    const u16* Ab = Asb + (t & 1) * 4096;
    const u16* Bb = Bsb + (t % 3) * 4096;
    bf16x8 a0 = *(const bf16x8*)&Ab[baseA];
    bf16x8 a1 = *(const bf16x8*)&Ab[baseA + 512];
    bf16x8 a2 = *(const bf16x8*)&Ab[baseA + 1024];
    bf16x8 a3 = *(const bf16x8*)&Ab[baseA + 1536];
    bf16x8 b0 = *(const bf16x8*)&Bb[baseB];
    bf16x8 b1 = *(const bf16x8*)&Bb[baseB + 512];
    bf16x8 b2 = *(const bf16x8*)&Bb[baseB + 1024];
    bf16x8 b3 = *(const bf16x8*)&Bb[baseB + 1536];
    if (t + 1 < NT) STG_A(t + 1);
    if (t + 2 < NT) STG_B(t + 2);
    asm volatile("s_waitcnt lgkmcnt(0)" ::: "memory");
    __builtin_amdgcn_sched_barrier(0);
    __builtin_amdgcn_s_setprio(1);
    acc[0][0] = __builtin_amdgcn_mfma_f32_16x16x32_bf16(a0, b0, acc[0][0], 0, 0, 0);
    acc[0][1] = __builtin_amdgcn_mfma_f32_16x16x32_bf16(a0, b1, acc[0][1], 0, 0, 0);
    acc[0][2] = __builtin_amdgcn_mfma_f32_16x16x32_bf16(a0, b2, acc[0][2], 0, 0, 0);
    acc[0][3] = __builtin_amdgcn_mfma_f32_16x16x32_bf16(a0, b3, acc[0][3], 0, 0, 0);
    acc[1][0] = __builtin_amdgcn_mfma_f32_16x16x32_bf16(a1, b0, acc[1][0], 0, 0, 0);
    acc[1][1] = __builtin_amdgcn_mfma_f32_16x16x32_bf16(a1, b1, acc[1][1], 0, 0, 0);
    acc[1][2] = __builtin_amdgcn_mfma_f32_16x16x32_bf16(a1, b2, acc[1][2], 0, 0, 0);
    acc[1][3] = __builtin_amdgcn_mfma_f32_16x16x32_bf16(a1, b3, acc[1][3], 0, 0, 0);
    acc[2][0] = __builtin_amdgcn_mfma_f32_16x16x32_bf16(a2, b0, acc[2][0], 0, 0, 0);
    acc[2][1] = __builtin_amdgcn_mfma_f32_16x16x32_bf16(a2, b1, acc[2][1], 0, 0, 0);
    acc[2][2] = __builtin_amdgcn_mfma_f32_16x16x32_bf16(a2, b2, acc[2][2], 0, 0, 0);
    acc[2][3] = __builtin_amdgcn_mfma_f32_16x16x32_bf16(a2, b3, acc[2][3], 0, 0, 0);
    acc[3][0] = __builtin_amdgcn_mfma_f32_16x16x32_bf16(a3, b0, acc[3][0], 0, 0, 0);
    acc[3][1] = __builtin_amdgcn_mfma_f32_16x16x32_bf16(a3, b1, acc[3][1], 0, 0, 0);
    acc[3][2] = __builtin_amdgcn_mfma_f32_16x16x32_bf16(a3, b2, acc[3][2], 0, 0, 0);
    acc[3][3] = __builtin_amdgcn_mfma_f32_16x16x32_bf16(a3, b3, acc[3][3], 0, 0, 0);
    __builtin_amdgcn_s_setprio(0);
    if (t < NT - 2) {
      asm volatile("s_waitcnt vmcnt(2)" ::: "memory");
    } else if (t == NT - 2) {
      asm volatile("s_waitcnt vmcnt(0)" ::: "memory");
    }
    __builtin_amdgcn_sched_barrier(0);
    if (t + 1 < NT) __builtin_amdgcn_s_barrier();
  }
#undef STG_A
#undef STG_B

  const int ocol0 = tn * 128 + wc * 64;
  const int orow0 = tm * 128 + wr * 64;

  if (!G1) {
    // ---- plain fp32+bias path (64B row segments, OK granularity)
#pragma unroll
    for (int mf = 0; mf < 4; ++mf)
#pragma unroll
      for (int nf = 0; nf < 4; ++nf) {
        const int col = ocol0 + nf * 16 + lr;
        const float bv = BIAS ? bias[col] : 0.0f;
#pragma unroll
        for (int q = 0; q < 4; ++q) {
          const int row = orow0 + mf * 16 + hi * 4 + q;
          ((float*)Cv)[(size_t)row * N + col] = acc[mf][nf][q] + bv;
        }
      }
  } else if (tn < 6) {
    // ---- q path: softmax, LDS-bounce, full-line 16B/lane stores
    __syncthreads();                         // all main-loop LDS reads done
    u16* wlds = lds + wave * 4352;           // per-wave [64][68]
#pragma unroll
    for (int mf = 0; mf < 4; ++mf) {
#pragma unroll
      for (int q = 0; q < 4; ++q) {
        float v0 = acc[mf][0][q], v1 = acc[mf][1][q];
        float v2 = acc[mf][2][q], v3 = acc[mf][3][q];
        float mx = fmaxf(fmaxf(v0, v1), fmaxf(v2, v3));
#pragma unroll
        for (int s = 1; s <= 8; s <<= 1) mx = fmaxf(mx, __shfl_xor(mx, s, 64));
        float e0 = __expf(v0 - mx), e1 = __expf(v1 - mx);
        float e2 = __expf(v2 - mx), e3 = __expf(v3 - mx);
        float sm = e0 + e1 + e2 + e3;
#pragma unroll
        for (int s = 1; s <= 8; s <<= 1) sm += __shfl_xor(sm, s, 64);
        float inv = 1.0f / sm;
        const int rw = mf * 16 + hi * 4 + q;
        wlds[rw * 68 + 0 * 16 + lr] = f2b(e0 * inv);
        wlds[rw * 68 + 1 * 16 + lr] = f2b(e1 * inv);
        wlds[rw * 68 + 2 * 16 + lr] = f2b(e2 * inv);
        wlds[rw * 68 + 3 * 16 + lr] = f2b(e3 * inv);
      }
    }
    // per-wave drain (own region, own data; lgkmcnt orders write->read)
#pragma unroll
    for (int it = 0; it < 8; ++it) {
      const int row = it * 8 + (lane >> 3);
      const int c8 = (lane & 7) * 8;
      u16x8 v = *(const u16x8*)&wlds[row * 68 + c8];
      *(u16x8*)((u16*)Cv + (size_t)(orow0 + row) * 768 + ocol0 + c8) = v;
    }
  } else {
    // ---- kv head tile: softmax k (wc==0), transpose to LDS, ctx = k^T v
    const int h = tn - 6;
    if (wc == 0) {
#pragma unroll
      for (int mf = 0; mf < 4; ++mf)
#pragma unroll
        for (int q = 0; q < 4; ++q) {
          float v0 = acc[mf][0][q], v1 = acc[mf][1][q];
          float v2 = acc[mf][2][q], v3 = acc[mf][3][q];
          float mx = fmaxf(fmaxf(v0, v1), fmaxf(v2, v3));
#pragma unroll
          for (int s = 1; s <= 8; s <<= 1) mx = fmaxf(mx, __shfl_xor(mx, s, 64));
          float e0 = __expf(v0 - mx), e1 = __expf(v1 - mx);
          float e2 = __expf(v2 - mx), e3 = __expf(v3 - mx);
          float sm = e0 + e1 + e2 + e3;
#pragma unroll
          for (int s = 1; s <= 8; s <<= 1) sm += __shfl_xor(sm, s, 64);
          float inv = 1.0f / sm;
          acc[mf][0][q] = e0 * inv; acc[mf][1][q] = e1 * inv;
          acc[mf][2][q] = e2 * inv; acc[mf][3][q] = e3 * inv;
        }
    }
    __syncthreads();                         // all main-loop LDS reads done
    u16* kT = lds;                           // [64][136]
    u16* vT = lds + 8704;                    // [64][136]
    u16* tgt = wc ? vT : kT;
#pragma unroll
    for (int mf = 0; mf < 4; ++mf)
#pragma unroll
      for (int nf = 0; nf < 4; ++nf)
#pragma unroll
        for (int q = 0; q < 4; ++q)
          tgt[(nf * 16 + lr) * 136 + wr * 64 + mf * 16 + hi * 4 + q] =
              f2b(acc[mf][nf][q]);
    __syncthreads();
    f32x4 cacc[4] = {};
#pragma unroll
    for (int ks = 0; ks < 4; ++ks) {
      bf16x8 ak = *(const bf16x8*)&kT[(wave * 16 + lr) * 136 + ks * 32 + hi * 8];
#pragma unroll
      for (int ef = 0; ef < 4; ++ef) {
        bf16x8 bv = *(const bf16x8*)&vT[(ef * 16 + lr) * 136 + ks * 32 + hi * 8];
        cacc[ef] = __builtin_amdgcn_mfma_f32_16x16x32_bf16(ak, bv, cacc[ef], 0, 0, 0);
      }
    }
    __syncthreads();                         // kT/vT reads done; reuse as bounce
    u16* blds = lds;                         // [64][68]
#pragma unroll
    for (int ef = 0; ef < 4; ++ef)
#pragma unroll
      for (int q = 0; q < 4; ++q)
        blds[(wave * 16 + hi * 4 + q) * 68 + ef * 16 + lr] = f2b(cacc[ef][q]);
    __syncthreads();
    u16* pdst = (u16*)Pw + ((size_t)tm * 12 + h) * 4096;
#pragma unroll
    for (int it = 0; it < 2; ++it) {
      const int seg = it * 256 + tid;
      const int row = seg >> 3, c8 = (seg & 7) * 8;
      u16x8 v = *(const u16x8*)&blds[row * 68 + c8];
      *(u16x8*)(pdst + row * 64 + c8) = v;
    }
  }
}

// ---- reduce bf16 partials (32 m-tiles) -> ctxD[bh][d*64+e] bf16 ----
__global__ __launch_bounds__(256) void ctx_reduce_kernel(const u16* __restrict__ partial,
                                                         u16* __restrict__ ctxD) {
  int idx = (blockIdx.x * 256 + threadIdx.x) * 8;   // over 96*4096
  int bh = idx >> 12;
  int b = bh / 12, h = bh % 12;
  int de = idx & 4095;
  const u16* base = partial + ((size_t)(b * 32) * 12 + h) * 4096 + de;
  float s[8] = {};
#pragma unroll 4
  for (int i = 0; i < 32; ++i) {
    u16x8 v = *(const u16x8*)(base + (size_t)i * 49152);
#pragma unroll
    for (int j = 0; j < 8; ++j) s[j] += b2f(v[j]);
  }
  u16x8 o;
#pragma unroll
  for (int j = 0; j < 8; ++j) o[j] = f2b(s[j]);
  *(u16x8*)(ctxD + (size_t)bh * 4096 + de) = o;
}

// ---- W2T[b][c'][h*64+d] = sum_e WprojT[c'][h*64+e] * ctxD[bh][d*64+e] ----
__global__ __launch_bounds__(256) void make_w2_kernel(const u16* __restrict__ WprojT,
                                                      const u16* __restrict__ ctxD,
                                                      u16* __restrict__ BT2) {
  __shared__ u16 qs[128 * 64];
  __shared__ u16 cs[64 * 64];
  int bid = blockIdx.x;
  int b = bid / 72, rest = bid % 72;
  int h = rest / 6, ct = rest % 6;
  int bh = b * 12 + h;
  int tid = threadIdx.x, wave = tid >> 6, lane = tid & 63;
  int lr = lane & 15, lk = (lane >> 4) << 3;
#pragma unroll
  for (int it = 0; it < 4; ++it) {
    int u = it * 256 + tid;
    int r = u >> 3, c8 = (u & 7) * 8;
    gload_lds16(WprojT + (size_t)(ct * 128 + r) * 768 + h * 64 + c8,
                &qs[(it * 256 + wave * 64) * 8]);
  }
#pragma unroll
  for (int it = 0; it < 2; ++it) {
    int u = it * 256 + tid;
    gload_lds16(ctxD + (size_t)bh * 4096 + u * 8, &cs[(it * 256 + wave * 64) * 8]);
  }
  asm volatile("s_waitcnt vmcnt(0)" ::: "memory");
  __syncthreads();
  f32x4 acc[2][4] = {};
#pragma unroll
  for (int ks = 0; ks < 2; ++ks) {
    bf16x8 bv[4];
#pragma unroll
    for (int jt = 0; jt < 4; ++jt) bv[jt] = *(const bf16x8*)&cs[(jt * 16 + lr) * 64 + ks * 32 + lk];
#pragma unroll
    for (int i = 0; i < 2; ++i) {
      bf16x8 af = *(const bf16x8*)&qs[(wave * 32 + i * 16 + lr) * 64 + ks * 32 + lk];
#pragma unroll
      for (int jt = 0; jt < 4; ++jt)
        acc[i][jt] = __builtin_amdgcn_mfma_f32_16x16x32_bf16(af, bv[jt], acc[i][jt], 0, 0, 0);
    }
  }
#pragma unroll
  for (int i = 0; i < 2; ++i)
#pragma unroll
    for (int jt = 0; jt < 4; ++jt)
#pragma unroll
      for (int q = 0; q < 4; ++q) {
        int cp = ct * 128 + wave * 32 + i * 16 + (lane >> 4) * 4 + q;
        int col = h * 64 + jt * 16 + lr;
        BT2[(size_t)b * 589824 + (size_t)cp * 768 + col] = f2b(acc[i][jt][q]);
      }
}

extern "C" void kernel_launch(void* const* d_in, const int* in_sizes, int n_in,
                              void* d_out, int out_size, void* d_ws, size_t ws_size,
                              hipStream_t stream) {
  const float* x = (const float*)d_in[0];
  const float* Wqkv = (const float*)d_in[1];
  const float* Wproj = (const float*)d_in[2];
  const float* bproj = (const float*)d_in[3];
  float* out = (float*)d_out;
  char* ws = (char*)d_ws;

  u16* xb      = (u16*)(ws);                     // 32768*768*2      = 50331648
  u16* WqkvT   = (u16*)(ws + 50331648);          // 2304*768*2       = 3538944
  u16* WprojT  = (u16*)(ws + 53870592);          // 768*768*2        = 1179648
  u16* qbuf    = (u16*)(ws + 55050240);          // 32768*768*2      = 50331648
  u16* partial = (u16*)(ws + 105381888);         // 256*12*4096*2    = 25165824
  u16* ctxD    = (u16*)(ws + 130547712);         // 96*4096*2        = 786432
  u16* BT2     = (u16*)(ws + 131334144);         // 8*768*768*2      = 9437184

  cast_x_kernel<<<2048, 256, 0, stream>>>(x, xb, (size_t)(32768ll * 768 / 8));
  transpose_cast_kernel<true><<<(768 / 32) * (2304 / 32), 256, 0, stream>>>(Wqkv, WqkvT, 768, 2304);
  transpose_cast_kernel<false><<<(768 / 32) * (768 / 32), 256, 0, stream>>>(Wproj, WprojT, 768, 768);

  // GEMM1: q -> softmax -> qbuf ; kv head tiles -> softmax k -> bf16 ctx partials
  gemm128_kernel<true, false, false><<<(32768 / 128) * (2304 / 128), 256, 0, stream>>>(
      xb, WqkvT, (void*)qbuf, (void*)partial, nullptr, 2304, 768, 2304 / 128);

  ctx_reduce_kernel<<<(96 * 4096) / (256 * 8), 256, 0, stream>>>(partial, ctxD);
  make_w2_kernel<<<8 * 12 * 6, 256, 0, stream>>>(WprojT, ctxD, BT2);

  // GEMM3: out = qbuf @ W2T_b^T + bias  (contiguous A, per-batch B)
  gemm128_kernel<false, true, true><<<(32768 / 128) * (768 / 128), 256, 0, stream>>>(
      qbuf, BT2, (void*)out, nullptr, bproj, 768, 768, 768 / 128);
}